// Round 8
// baseline (236.582 us; speedup 1.0000x reference)
//
#include <hip/hip_runtime.h>
#include <hip/hip_bf16.h>
#include <stdint.h>

// B=4, C=64, N=16384, K=16, CO=64 (fp32 I/O, int32 idx)
// 4-dispatch pipeline, NO global atomics:
//  k1 gemm:   y1=(W1+W2)x, y2=W2x -> bf16 (B,N,64) channel-pair packed
//  k2 gather: pair-packed gather, min/max + BN-stat partials -> plain stores
//  k3 reduce: 1 block sums partials[1024][128] -> scale/bias sb[128]
//  k4 out:    affine + leaky + transpose (B,N,64)->(B,64,N)
#define NDIM 16384
#define KNB 16
#define BNK_F 1048576.0f

union Pack4 { __hip_bfloat16 h[4]; uint2 u; };

// ---------------- Kernel 1: y1/y2 GEMM (packed-W LDS) ----------------
__global__ __launch_bounds__(256) void gemm_y_kernel(
    const float* __restrict__ x,            // (B, 64, N)
    const float* __restrict__ W,            // (64, 128)
    __hip_bfloat16* __restrict__ y1,        // (B, N, 64) bf16
    __hip_bfloat16* __restrict__ y2)        // (B, N, 64) bf16
{
    __shared__ alignas(16) unsigned int lds_w[64 * 68]; // (w1+w2 | w2<<16) bf16
    __shared__ alignas(16) float        lds_x[64 * 68];

    const int tid = threadIdx.x;
    const int b  = blockIdx.x >> 8;
    const int n0 = (blockIdx.x & 255) << 6;

    for (int i = tid; i < 4096; i += 256) {
        int c = i & 63, o = i >> 6;
        float w1 = W[o * 128 + c];
        float w2 = W[o * 128 + 64 + c];
        unsigned int u12 = (unsigned int)__bfloat16_as_ushort(__float2bfloat16(w1 + w2));
        unsigned int u2  = (unsigned int)__bfloat16_as_ushort(__float2bfloat16(w2));
        lds_w[c * 68 + o] = u12 | (u2 << 16);
    }
    const float* xb = x + (size_t)b * 64 * NDIM + n0;
    for (int i = tid; i < 4096; i += 256) {
        int nl = i & 63, c = i >> 6;
        lds_x[c * 68 + nl] = xb[(size_t)c * NDIM + nl];
    }
    __syncthreads();

    const int o0  = (tid & 15) * 4;
    const int nl0 = (tid >> 4) * 4;
    float acc1[4][4] = {}, acc2[4][4] = {};
    #pragma unroll 4
    for (int c = 0; c < 64; ++c) {
        float4 xv = *(const float4*)&lds_x[c * 68 + nl0];
        uint4  wv = *(const uint4*)&lds_w[c * 68 + o0];
        const float xa[4] = { xv.x, xv.y, xv.z, xv.w };
        const unsigned int wu[4] = { wv.x, wv.y, wv.z, wv.w };
        #pragma unroll
        for (int j = 0; j < 4; ++j) {
            float w12 = __uint_as_float(wu[j] << 16);
            float w2f = __uint_as_float(wu[j] & 0xffff0000u);
            #pragma unroll
            for (int i = 0; i < 4; ++i) {
                acc1[i][j] = fmaf(w12, xa[i], acc1[i][j]);
                acc2[i][j] = fmaf(w2f, xa[i], acc2[i][j]);
            }
        }
    }
    const size_t bn0 = (size_t)b * NDIM + n0;
    #pragma unroll
    for (int i = 0; i < 4; ++i) {
        Pack4 p1, p2;
        #pragma unroll
        for (int j = 0; j < 4; ++j) {
            p1.h[j] = __float2bfloat16(acc1[i][j]);
            p2.h[j] = __float2bfloat16(acc2[i][j]);
        }
        size_t off = (bn0 + nl0 + i) * 64 + o0;
        *(uint2*)(y1 + off) = p1.u;
        *(uint2*)(y2 + off) = p2.u;
    }
}

// ---------------- Kernel 2: packed gather + extremes + stat partials ----------------
// 1024 blocks x 256. XCD-pinned: xcd=g&7 -> batch b=xcd>>1 (2 MB y2/batch in L2).
// Wave handles 2 rows at once: lanes 0-31 rowA (channels 2c2,2c2+1), lanes 32-63 rowB.
__global__ __launch_bounds__(256, 4) void gather_kernel(
    const unsigned* __restrict__ y1p,        // (B,N,32) bf16-pairs
    const unsigned* __restrict__ y2p,        // (B,N,32) bf16-pairs
    const int* __restrict__ ei,              // (B, N, 16)
    const float* __restrict__ gamma,         // (64)
    unsigned* __restrict__ hselp,            // (B,N,32) bf16-pairs
    float* __restrict__ partials)            // (1024, 128): [0..63]=sum, [64..127]=sumsq
{
    const int tid  = threadIdx.x;
    const int w    = __builtin_amdgcn_readfirstlane(tid >> 6);  // wave-uniform
    const int lane = tid & 63;
    const int half = lane >> 5;              // 0: rowA, 1: rowB
    const int c2   = lane & 31;              // channel-pair index
    const int g    = blockIdx.x;             // 0..1023
    const int xcd  = g & 7;
    const int b    = xcd >> 1;
    const int hlf  = xcd & 1;
    const int lb   = g >> 3;                 // 0..127
    const int row0 = b * NDIM + hlf * 8192 + lb * 64 + w * 16;

    const unsigned sgn0 = (gamma[2 * c2]     >= 0.0f) ? 0x80000000u : 0u;
    const unsigned sgn1 = (gamma[2 * c2 + 1] >= 0.0f) ? 0x80000000u : 0u;
    const unsigned* y2b = y2p + ((size_t)b * NDIM) * 32 + c2;

    float ssum0 = 0.f, ssum1 = 0.f, ssq0 = 0.f, ssq1 = 0.f;

    for (int rp = 0; rp < 16; rp += 4) {
        const int ra = row0 + rp;
        const int rb = row0 + rp + 2;
        const int* iA = ei + (size_t)ra * KNB;        // wave-uniform -> s_load
        const int* iB = ei + (size_t)(ra + 1) * KNB;
        const int* iC = ei + (size_t)rb * KNB;
        const int* iD = ei + (size_t)(rb + 1) * KNB;

        unsigned u0[KNB], u1[KNB];
        #pragma unroll
        for (int k = 0; k < KNB; ++k) {
            int j = half ? iB[k] : iA[k];
            u0[k] = y2b[(size_t)j * 32];
        }
        #pragma unroll
        for (int k = 0; k < KNB; ++k) {
            int j = half ? iD[k] : iC[k];
            u1[k] = y2b[(size_t)j * 32];
        }
        const unsigned y1u0 = y1p[(size_t)(ra + half) * 32 + c2];
        const unsigned y1u1 = y1p[(size_t)(rb + half) * 32 + c2];

        #pragma unroll 2
        for (int p = 0; p < 2; ++p) {
            const unsigned* u = (p == 0) ? u0 : u1;
            const unsigned y1u = (p == 0) ? y1u0 : y1u1;
            const int rw = ((p == 0) ? ra : rb) + half;

            float s20 = 0.f, s21 = 0.f, q20 = 0.f, q21 = 0.f;
            float M0 = -3.402823e38f, M1 = -3.402823e38f;
            #pragma unroll
            for (int k = 0; k < KNB; ++k) {
                unsigned lo = u[k] << 16;
                unsigned hi = u[k] & 0xffff0000u;
                float v0 = __uint_as_float(lo);
                float v1 = __uint_as_float(hi);
                s20 += v0;               s21 += v1;
                q20 = fmaf(v0, v0, q20); q21 = fmaf(v1, v1, q21);
                M0 = fmaxf(M0, __uint_as_float(lo ^ sgn0));
                M1 = fmaxf(M1, __uint_as_float(hi ^ sgn1));
            }
            const float y1lo = __uint_as_float(y1u << 16);
            const float y1hi = __uint_as_float(y1u & 0xffff0000u);
            const float e0 = __uint_as_float(__float_as_uint(M0) ^ sgn0);
            const float e1 = __uint_as_float(__float_as_uint(M1) ^ sgn1);
            const float h0 = y1lo - e0;
            const float h1 = y1hi - e1;
            unsigned pk = (unsigned)__bfloat16_as_ushort(__float2bfloat16(h0))
                        | ((unsigned)__bfloat16_as_ushort(__float2bfloat16(h1)) << 16);
            hselp[(size_t)rw * 32 + c2] = pk;
            // sum_k (y1-v) = 16 y1 - s2 ; sum_k (y1-v)^2 = (16 y1 - 2 s2) y1 + q2
            ssum0 += 16.f * y1lo - s20;
            ssum1 += 16.f * y1hi - s21;
            ssq0  += fmaf(fmaf(-2.f, s20, 16.f * y1lo), y1lo, q20);
            ssq1  += fmaf(fmaf(-2.f, s21, 16.f * y1hi), y1hi, q21);
        }
    }

    __shared__ float rs[8][64];
    __shared__ float rq[8][64];
    rs[w * 2 + half][c2 * 2]     = ssum0;
    rs[w * 2 + half][c2 * 2 + 1] = ssum1;
    rq[w * 2 + half][c2 * 2]     = ssq0;
    rq[w * 2 + half][c2 * 2 + 1] = ssq1;
    __syncthreads();
    if (tid < 128) {
        const int c = tid & 63;
        float v = 0.f;
        if (tid < 64) {
            #pragma unroll
            for (int r = 0; r < 8; ++r) v += rs[r][c];
        } else {
            #pragma unroll
            for (int r = 0; r < 8; ++r) v += rq[r][c];
        }
        partials[(size_t)g * 128 + tid] = v;   // plain coalesced store, no atomics
    }
}

// ---------------- Kernel 3: reduce partials -> scale/bias ----------------
__global__ __launch_bounds__(256) void reduce_kernel(
    const float* __restrict__ partials,      // (1024, 128)
    const float* __restrict__ gamma,
    const float* __restrict__ beta,
    float* __restrict__ sb)                  // [0..63]=scale, [64..127]=bias
{
    __shared__ float lds[256];
    const int tid = threadIdx.x;
    const int c   = tid & 127;
    float acc = 0.f;
    for (int r = tid >> 7; r < 1024; r += 2)
        acc += partials[(size_t)r * 128 + c];
    lds[tid] = acc;
    __syncthreads();
    if (tid < 64) {
        float S = lds[tid]      + lds[tid + 128];
        float Q = lds[tid + 64] + lds[tid + 192];
        float mean = S * (1.0f / BNK_F);
        float var  = Q * (1.0f / BNK_F) - mean * mean;
        float s    = gamma[tid] * rsqrtf(var + 1e-5f);
        sb[tid]      = s;
        sb[64 + tid] = beta[tid] - mean * s;
    }
}

// ---------------- Kernel 4: affine + leaky + transpose ----------------
__global__ __launch_bounds__(256) void out_kernel(
    const unsigned* __restrict__ hselp,      // (B,N,32) bf16-pairs
    const float* __restrict__ sb,
    float* __restrict__ out)                 // (B, 64, N)
{
    __shared__ float tile[64 * 65];
    __shared__ float sc[64], bi[64];
    const int tid = threadIdx.x;
    if (tid < 128) {
        if (tid < 64) sc[tid] = sb[tid];
        else          bi[tid - 64] = sb[tid];
    }
    __syncthreads();

    const int b  = blockIdx.x >> 8;
    const int n0 = (blockIdx.x & 255) << 6;
    const size_t bn0 = (size_t)b * NDIM + n0;
    const int c2 = tid & 31;
    const int r0 = tid >> 5;                 // 8 rows per pass

    for (int r = r0; r < 64; r += 8) {
        unsigned u = hselp[(bn0 + r) * 32 + c2];
        float v0 = fmaf(sc[2 * c2],     __uint_as_float(u << 16),          bi[2 * c2]);
        float v1 = fmaf(sc[2 * c2 + 1], __uint_as_float(u & 0xffff0000u), bi[2 * c2 + 1]);
        v0 = (v0 >= 0.f) ? v0 : 0.2f * v0;
        v1 = (v1 >= 0.f) ? v1 : 0.2f * v1;
        tile[r * 65 + 2 * c2]     = v0;
        tile[r * 65 + 2 * c2 + 1] = v1;
    }
    __syncthreads();
    const int lane = tid & 63;
    for (int o = tid >> 6; o < 64; o += 4)
        out[((size_t)(b * 64 + o) << 14) + n0 + lane] = tile[lane * 65 + o];
}

extern "C" void kernel_launch(void* const* d_in, const int* in_sizes, int n_in,
                              void* d_out, int out_size, void* d_ws, size_t ws_size,
                              hipStream_t stream) {
    const float* x     = (const float*)d_in[0];
    const int*   ei    = (const int*)d_in[1];
    const float* W     = (const float*)d_in[2];
    const float* gamma = (const float*)d_in[3];
    const float* beta  = (const float*)d_in[4];
    float* out = (float*)d_out;

    char* ws = (char*)d_ws;
    __hip_bfloat16* y1    = (__hip_bfloat16*)(ws);                // 8 MiB
    __hip_bfloat16* y2    = (__hip_bfloat16*)(ws + 8388608);      // 8 MiB
    unsigned*       hselp = (unsigned*)(ws + 16777216);           // 8 MiB (bf16 pairs)
    float*          part  = (float*)(ws + 25165824);              // 512 KiB
    float*          sb    = (float*)(ws + 25165824 + 524288);     // 512 B

    gemm_y_kernel <<<dim3(1024), dim3(256), 0, stream>>>(x, W, y1, y2);
    gather_kernel <<<dim3(1024), dim3(256), 0, stream>>>((const unsigned*)y1, (const unsigned*)y2,
                                                         ei, gamma, hselp, part);
    reduce_kernel <<<dim3(1),    dim3(256), 0, stream>>>(part, gamma, beta, sb);
    out_kernel    <<<dim3(1024), dim3(256), 0, stream>>>(hselp, sb, out);
}

// Round 9
// 179.260 us; speedup vs baseline: 1.3198x; 1.3198x over previous
//
#include <hip/hip_runtime.h>
#include <hip/hip_bf16.h>
#include <stdint.h>

// B=4, C=64, N=16384, K=16, CO=64 (fp32 I/O, int32 idx)
// 4-dispatch pipeline:
//  k1 gemm:   y1=(W1+W2)x, y2=W2x -> bf16 (B,N,64) pair-packed; zeroes stats
//  k2 gather: 2048 blocks (8 waves/CU target) pair-packed gather, partials stores
//  k3 reduce: 64 blocks sum partials[2048][128] -> atomicAdd stats[128]
//  k4 out:    finalize BN inline from stats + affine + leaky + transpose
#define NDIM 16384
#define KNB 16
#define BNK_F 1048576.0f

union Pack4 { __hip_bfloat16 h[4]; uint2 u; };

// ---------------- Kernel 1: y1/y2 GEMM (packed-W LDS) ----------------
__global__ __launch_bounds__(256) void gemm_y_kernel(
    const float* __restrict__ x,            // (B, 64, N)
    const float* __restrict__ W,            // (64, 128)
    __hip_bfloat16* __restrict__ y1,        // (B, N, 64) bf16
    __hip_bfloat16* __restrict__ y2,        // (B, N, 64) bf16
    float* __restrict__ stats)              // zeroed here
{
    __shared__ alignas(16) unsigned int lds_w[64 * 68]; // (w1+w2 | w2<<16) bf16
    __shared__ alignas(16) float        lds_x[64 * 68];

    const int tid = threadIdx.x;
    if (blockIdx.x == 0 && tid < 128) stats[tid] = 0.0f;

    const int b  = blockIdx.x >> 8;
    const int n0 = (blockIdx.x & 255) << 6;

    for (int i = tid; i < 4096; i += 256) {
        int c = i & 63, o = i >> 6;
        float w1 = W[o * 128 + c];
        float w2 = W[o * 128 + 64 + c];
        unsigned int u12 = (unsigned int)__bfloat16_as_ushort(__float2bfloat16(w1 + w2));
        unsigned int u2  = (unsigned int)__bfloat16_as_ushort(__float2bfloat16(w2));
        lds_w[c * 68 + o] = u12 | (u2 << 16);
    }
    const float* xb = x + (size_t)b * 64 * NDIM + n0;
    for (int i = tid; i < 4096; i += 256) {
        int nl = i & 63, c = i >> 6;
        lds_x[c * 68 + nl] = xb[(size_t)c * NDIM + nl];
    }
    __syncthreads();

    const int o0  = (tid & 15) * 4;
    const int nl0 = (tid >> 4) * 4;
    float acc1[4][4] = {}, acc2[4][4] = {};
    #pragma unroll 4
    for (int c = 0; c < 64; ++c) {
        float4 xv = *(const float4*)&lds_x[c * 68 + nl0];
        uint4  wv = *(const uint4*)&lds_w[c * 68 + o0];
        const float xa[4] = { xv.x, xv.y, xv.z, xv.w };
        const unsigned int wu[4] = { wv.x, wv.y, wv.z, wv.w };
        #pragma unroll
        for (int j = 0; j < 4; ++j) {
            float w12 = __uint_as_float(wu[j] << 16);
            float w2f = __uint_as_float(wu[j] & 0xffff0000u);
            #pragma unroll
            for (int i = 0; i < 4; ++i) {
                acc1[i][j] = fmaf(w12, xa[i], acc1[i][j]);
                acc2[i][j] = fmaf(w2f, xa[i], acc2[i][j]);
            }
        }
    }
    const size_t bn0 = (size_t)b * NDIM + n0;
    #pragma unroll
    for (int i = 0; i < 4; ++i) {
        Pack4 p1, p2;
        #pragma unroll
        for (int j = 0; j < 4; ++j) {
            p1.h[j] = __float2bfloat16(acc1[i][j]);
            p2.h[j] = __float2bfloat16(acc2[i][j]);
        }
        size_t off = (bn0 + nl0 + i) * 64 + o0;
        *(uint2*)(y1 + off) = p1.u;
        *(uint2*)(y2 + off) = p2.u;
    }
}

// ---------------- Kernel 2: packed gather + extremes + stat partials ----------------
// 2048 blocks x 256 (8 blocks/CU target). XCD-pinned: xcd=g&7 -> batch b=xcd>>1.
// Wave handles 2 rows at once: lanes 0-31 rowA (channels 2c2,2c2+1), lanes 32-63 rowB.
__global__ __launch_bounds__(256, 8) void gather_kernel(
    const unsigned* __restrict__ y1p,        // (B,N,32) bf16-pairs
    const unsigned* __restrict__ y2p,        // (B,N,32) bf16-pairs
    const int* __restrict__ ei,              // (B, N, 16)
    const float* __restrict__ gamma,         // (64)
    unsigned* __restrict__ hselp,            // (B,N,32) bf16-pairs
    float* __restrict__ partials)            // (2048, 128): [0..63]=sum, [64..127]=sumsq
{
    const int tid  = threadIdx.x;
    const int w    = __builtin_amdgcn_readfirstlane(tid >> 6);  // wave-uniform
    const int lane = tid & 63;
    const int half = lane >> 5;              // 0: rowA, 1: rowB
    const int c2   = lane & 31;              // channel-pair index
    const int g    = blockIdx.x;             // 0..2047
    const int xcd  = g & 7;
    const int b    = xcd >> 1;
    const int hlf  = xcd & 1;
    const int lb   = g >> 3;                 // 0..255
    const int row0 = b * NDIM + hlf * 8192 + lb * 32 + w * 8;

    const unsigned sgn0 = (gamma[2 * c2]     >= 0.0f) ? 0x80000000u : 0u;
    const unsigned sgn1 = (gamma[2 * c2 + 1] >= 0.0f) ? 0x80000000u : 0u;
    const unsigned* y2b = y2p + ((size_t)b * NDIM) * 32 + c2;

    float ssum0 = 0.f, ssum1 = 0.f, ssq0 = 0.f, ssq1 = 0.f;

    #pragma unroll
    for (int rp = 0; rp < 8; rp += 4) {
        const int ra = row0 + rp;
        const int rb = row0 + rp + 2;
        const int* iA = ei + (size_t)ra * KNB;        // wave-uniform -> s_load
        const int* iB = ei + (size_t)(ra + 1) * KNB;
        const int* iC = ei + (size_t)rb * KNB;
        const int* iD = ei + (size_t)(rb + 1) * KNB;

        unsigned u0[KNB], u1[KNB];
        #pragma unroll
        for (int k = 0; k < KNB; ++k) {
            int j = half ? iB[k] : iA[k];
            u0[k] = y2b[(size_t)j * 32];
        }
        #pragma unroll
        for (int k = 0; k < KNB; ++k) {
            int j = half ? iD[k] : iC[k];
            u1[k] = y2b[(size_t)j * 32];
        }
        const unsigned y1u0 = y1p[(size_t)(ra + half) * 32 + c2];
        const unsigned y1u1 = y1p[(size_t)(rb + half) * 32 + c2];

        #pragma unroll 2
        for (int p = 0; p < 2; ++p) {
            const unsigned* u = (p == 0) ? u0 : u1;
            const unsigned y1u = (p == 0) ? y1u0 : y1u1;
            const int rw = ((p == 0) ? ra : rb) + half;

            float s20 = 0.f, s21 = 0.f, q20 = 0.f, q21 = 0.f;
            float M0 = -3.402823e38f, M1 = -3.402823e38f;
            #pragma unroll
            for (int k = 0; k < KNB; ++k) {
                unsigned lo = u[k] << 16;
                unsigned hi = u[k] & 0xffff0000u;
                float v0 = __uint_as_float(lo);
                float v1 = __uint_as_float(hi);
                s20 += v0;               s21 += v1;
                q20 = fmaf(v0, v0, q20); q21 = fmaf(v1, v1, q21);
                M0 = fmaxf(M0, __uint_as_float(lo ^ sgn0));
                M1 = fmaxf(M1, __uint_as_float(hi ^ sgn1));
            }
            const float y1lo = __uint_as_float(y1u << 16);
            const float y1hi = __uint_as_float(y1u & 0xffff0000u);
            const float e0 = __uint_as_float(__float_as_uint(M0) ^ sgn0);
            const float e1 = __uint_as_float(__float_as_uint(M1) ^ sgn1);
            const float h0 = y1lo - e0;
            const float h1 = y1hi - e1;
            unsigned pk = (unsigned)__bfloat16_as_ushort(__float2bfloat16(h0))
                        | ((unsigned)__bfloat16_as_ushort(__float2bfloat16(h1)) << 16);
            hselp[(size_t)rw * 32 + c2] = pk;
            // sum_k (y1-v) = 16 y1 - s2 ; sum_k (y1-v)^2 = (16 y1 - 2 s2) y1 + q2
            ssum0 += 16.f * y1lo - s20;
            ssum1 += 16.f * y1hi - s21;
            ssq0  += fmaf(fmaf(-2.f, s20, 16.f * y1lo), y1lo, q20);
            ssq1  += fmaf(fmaf(-2.f, s21, 16.f * y1hi), y1hi, q21);
        }
    }

    __shared__ float rs[8][64];
    __shared__ float rq[8][64];
    rs[w * 2 + half][c2 * 2]     = ssum0;
    rs[w * 2 + half][c2 * 2 + 1] = ssum1;
    rq[w * 2 + half][c2 * 2]     = ssq0;
    rq[w * 2 + half][c2 * 2 + 1] = ssq1;
    __syncthreads();
    if (tid < 128) {
        const int c = tid & 63;
        float v = 0.f;
        if (tid < 64) {
            #pragma unroll
            for (int r = 0; r < 8; ++r) v += rs[r][c];
        } else {
            #pragma unroll
            for (int r = 0; r < 8; ++r) v += rq[r][c];
        }
        partials[(size_t)g * 128 + tid] = v;   // plain coalesced store
    }
}

// ---------------- Kernel 3: parallel reduce partials -> stats ----------------
// 64 blocks x 256: block j sums rows j*32..j*32+31; tid=(col 0..127, q=tid>>7)
__global__ __launch_bounds__(256) void reduce_kernel(
    const float* __restrict__ partials,      // (2048, 128)
    float* __restrict__ stats)               // [0..63]=sum, [64..127]=sumsq
{
    __shared__ float lds[256];
    const int tid = threadIdx.x;
    const int c   = tid & 127;
    const int q   = tid >> 7;                // 0/1: rows 16q..16q+15 of this block's 32
    const int r0  = blockIdx.x * 32 + q * 16;
    float acc = 0.f;
    #pragma unroll
    for (int r = 0; r < 16; ++r)
        acc += partials[(size_t)(r0 + r) * 128 + c];
    lds[tid] = acc;
    __syncthreads();
    if (tid < 128) atomicAdd(&stats[tid], lds[tid] + lds[tid + 128]);
}

// ---------------- Kernel 4: finalize + affine + leaky + transpose ----------------
__global__ __launch_bounds__(256) void out_kernel(
    const unsigned* __restrict__ hselp,      // (B,N,32) bf16-pairs
    const float* __restrict__ stats,
    const float* __restrict__ gamma,
    const float* __restrict__ beta,
    float* __restrict__ out)                 // (B, 64, N)
{
    __shared__ float tile[64 * 65];
    __shared__ float sc[64], bi[64];
    const int tid = threadIdx.x;
    if (tid < 64) {
        float mean = stats[tid] * (1.0f / BNK_F);
        float var  = stats[64 + tid] * (1.0f / BNK_F) - mean * mean;
        float s    = gamma[tid] * rsqrtf(var + 1e-5f);
        sc[tid] = s;
        bi[tid] = beta[tid] - mean * s;
    }
    __syncthreads();

    const int b  = blockIdx.x >> 8;
    const int n0 = (blockIdx.x & 255) << 6;
    const size_t bn0 = (size_t)b * NDIM + n0;
    const int c2 = tid & 31;
    const int r0 = tid >> 5;                 // 8 rows per pass

    for (int r = r0; r < 64; r += 8) {
        unsigned u = hselp[(bn0 + r) * 32 + c2];
        float v0 = fmaf(sc[2 * c2],     __uint_as_float(u << 16),          bi[2 * c2]);
        float v1 = fmaf(sc[2 * c2 + 1], __uint_as_float(u & 0xffff0000u), bi[2 * c2 + 1]);
        v0 = (v0 >= 0.f) ? v0 : 0.2f * v0;
        v1 = (v1 >= 0.f) ? v1 : 0.2f * v1;
        tile[r * 65 + 2 * c2]     = v0;
        tile[r * 65 + 2 * c2 + 1] = v1;
    }
    __syncthreads();
    const int lane = tid & 63;
    for (int o = tid >> 6; o < 64; o += 4)
        out[((size_t)(b * 64 + o) << 14) + n0 + lane] = tile[lane * 65 + o];
}

extern "C" void kernel_launch(void* const* d_in, const int* in_sizes, int n_in,
                              void* d_out, int out_size, void* d_ws, size_t ws_size,
                              hipStream_t stream) {
    const float* x     = (const float*)d_in[0];
    const int*   ei    = (const int*)d_in[1];
    const float* W     = (const float*)d_in[2];
    const float* gamma = (const float*)d_in[3];
    const float* beta  = (const float*)d_in[4];
    float* out = (float*)d_out;

    char* ws = (char*)d_ws;
    __hip_bfloat16* y1    = (__hip_bfloat16*)(ws);                // 8 MiB
    __hip_bfloat16* y2    = (__hip_bfloat16*)(ws + 8388608);      // 8 MiB
    unsigned*       hselp = (unsigned*)(ws + 16777216);           // 8 MiB (bf16 pairs)
    float*          part  = (float*)(ws + 25165824);              // 1 MiB
    float*          stats = (float*)(ws + 25165824 + 1048576);    // 512 B

    gemm_y_kernel <<<dim3(1024), dim3(256), 0, stream>>>(x, W, y1, y2, stats);
    gather_kernel <<<dim3(2048), dim3(256), 0, stream>>>((const unsigned*)y1, (const unsigned*)y2,
                                                         ei, gamma, hselp, part);
    reduce_kernel <<<dim3(64),   dim3(256), 0, stream>>>(part, stats);
    out_kernel    <<<dim3(1024), dim3(256), 0, stream>>>(hselp, stats, gamma, beta, out);
}

// Round 10
// 115.029 us; speedup vs baseline: 2.0567x; 1.5584x over previous
//
#include <hip/hip_runtime.h>
#include <hip/hip_bf16.h>
#include <stdint.h>

// B=4, C=64, N=16384, K=16, CO=64 (fp32 I/O, int32 idx)
// 4-dispatch pipeline:
//  k1 gemm:   y1=(W1+W2)x, y2=W2x -> bf16 (B,N,64) pair-packed; zeroes stats
//  k2 gather: 2048 blocks, single u[16] staging (NO spills - R9 lesson), partials stores
//  k3 reduce: 64 blocks sum partials[2048][128] -> atomicAdd stats[128]
//  k4 out:    finalize BN inline from stats + affine + leaky + transpose
#define NDIM 16384
#define KNB 16
#define BNK_F 1048576.0f

union Pack4 { __hip_bfloat16 h[4]; uint2 u; };

// ---------------- Kernel 1: y1/y2 GEMM (packed-W LDS) ----------------
__global__ __launch_bounds__(256) void gemm_y_kernel(
    const float* __restrict__ x,            // (B, 64, N)
    const float* __restrict__ W,            // (64, 128)
    __hip_bfloat16* __restrict__ y1,        // (B, N, 64) bf16
    __hip_bfloat16* __restrict__ y2,        // (B, N, 64) bf16
    float* __restrict__ stats)              // zeroed here
{
    __shared__ alignas(16) unsigned int lds_w[64 * 68]; // (w1+w2 | w2<<16) bf16
    __shared__ alignas(16) float        lds_x[64 * 68];

    const int tid = threadIdx.x;
    if (blockIdx.x == 0 && tid < 128) stats[tid] = 0.0f;

    const int b  = blockIdx.x >> 8;
    const int n0 = (blockIdx.x & 255) << 6;

    for (int i = tid; i < 4096; i += 256) {
        int c = i & 63, o = i >> 6;
        float w1 = W[o * 128 + c];
        float w2 = W[o * 128 + 64 + c];
        unsigned int u12 = (unsigned int)__bfloat16_as_ushort(__float2bfloat16(w1 + w2));
        unsigned int u2  = (unsigned int)__bfloat16_as_ushort(__float2bfloat16(w2));
        lds_w[c * 68 + o] = u12 | (u2 << 16);
    }
    const float* xb = x + (size_t)b * 64 * NDIM + n0;
    for (int i = tid; i < 4096; i += 256) {
        int nl = i & 63, c = i >> 6;
        lds_x[c * 68 + nl] = xb[(size_t)c * NDIM + nl];
    }
    __syncthreads();

    const int o0  = (tid & 15) * 4;
    const int nl0 = (tid >> 4) * 4;
    float acc1[4][4] = {}, acc2[4][4] = {};
    #pragma unroll 4
    for (int c = 0; c < 64; ++c) {
        float4 xv = *(const float4*)&lds_x[c * 68 + nl0];
        uint4  wv = *(const uint4*)&lds_w[c * 68 + o0];
        const float xa[4] = { xv.x, xv.y, xv.z, xv.w };
        const unsigned int wu[4] = { wv.x, wv.y, wv.z, wv.w };
        #pragma unroll
        for (int j = 0; j < 4; ++j) {
            float w12 = __uint_as_float(wu[j] << 16);
            float w2f = __uint_as_float(wu[j] & 0xffff0000u);
            #pragma unroll
            for (int i = 0; i < 4; ++i) {
                acc1[i][j] = fmaf(w12, xa[i], acc1[i][j]);
                acc2[i][j] = fmaf(w2f, xa[i], acc2[i][j]);
            }
        }
    }
    const size_t bn0 = (size_t)b * NDIM + n0;
    #pragma unroll
    for (int i = 0; i < 4; ++i) {
        Pack4 p1, p2;
        #pragma unroll
        for (int j = 0; j < 4; ++j) {
            p1.h[j] = __float2bfloat16(acc1[i][j]);
            p2.h[j] = __float2bfloat16(acc2[i][j]);
        }
        size_t off = (bn0 + nl0 + i) * 64 + o0;
        *(uint2*)(y1 + off) = p1.u;
        *(uint2*)(y2 + off) = p2.u;
    }
}

// ---------------- Kernel 2: packed gather + extremes + stat partials ----------------
// 2048 blocks x 256, XCD-pinned batches. Wave does 2 rows/pass (lanes 0-31 rowA,
// 32-63 rowB), 4 passes. Single u[16] staging: ~45 VGPRs, no spill (R9 lesson:
// launch_bounds(256,8) forced 32 VGPRs -> 268 MB scratch traffic).
__global__ __launch_bounds__(256, 4) void gather_kernel(
    const unsigned* __restrict__ y1p,        // (B,N,32) bf16-pairs
    const unsigned* __restrict__ y2p,        // (B,N,32) bf16-pairs
    const int* __restrict__ ei,              // (B, N, 16)
    const float* __restrict__ gamma,         // (64)
    unsigned* __restrict__ hselp,            // (B,N,32) bf16-pairs
    float* __restrict__ partials)            // (2048, 128): [0..63]=sum, [64..127]=sumsq
{
    const int tid  = threadIdx.x;
    const int w    = __builtin_amdgcn_readfirstlane(tid >> 6);  // wave-uniform
    const int lane = tid & 63;
    const int half = lane >> 5;              // 0: rowA, 1: rowB
    const int c2   = lane & 31;              // channel-pair index
    const int g    = blockIdx.x;             // 0..2047
    const int xcd  = g & 7;
    const int b    = xcd >> 1;
    const int hlf  = xcd & 1;
    const int lb   = g >> 3;                 // 0..255
    const int row0 = b * NDIM + hlf * 8192 + lb * 32 + w * 8;

    const unsigned sgn0 = (gamma[2 * c2]     >= 0.0f) ? 0x80000000u : 0u;
    const unsigned sgn1 = (gamma[2 * c2 + 1] >= 0.0f) ? 0x80000000u : 0u;
    const unsigned* y2b = y2p + ((size_t)b * NDIM) * 32 + c2;

    float ssum0 = 0.f, ssum1 = 0.f, ssq0 = 0.f, ssq1 = 0.f;

    for (int rp = 0; rp < 8; rp += 2) {
        const int ra = row0 + rp;            // lanes 0-31 -> row ra, lanes 32-63 -> ra+1
        const int* iA = ei + (size_t)ra * KNB;        // wave-uniform -> s_load
        const int* iB = ei + (size_t)(ra + 1) * KNB;

        unsigned u[KNB];
        #pragma unroll
        for (int k = 0; k < KNB; ++k) {
            int j = half ? iB[k] : iA[k];
            u[k] = y2b[(size_t)j * 32];
        }
        const unsigned y1u = y1p[(size_t)(ra + half) * 32 + c2];

        float s20 = 0.f, s21 = 0.f, q20 = 0.f, q21 = 0.f;
        float M0 = -3.402823e38f, M1 = -3.402823e38f;
        #pragma unroll
        for (int k = 0; k < KNB; ++k) {
            unsigned lo = u[k] << 16;
            unsigned hi = u[k] & 0xffff0000u;
            float v0 = __uint_as_float(lo);
            float v1 = __uint_as_float(hi);
            s20 += v0;               s21 += v1;
            q20 = fmaf(v0, v0, q20); q21 = fmaf(v1, v1, q21);
            M0 = fmaxf(M0, __uint_as_float(lo ^ sgn0));
            M1 = fmaxf(M1, __uint_as_float(hi ^ sgn1));
        }
        const float y1lo = __uint_as_float(y1u << 16);
        const float y1hi = __uint_as_float(y1u & 0xffff0000u);
        const float e0 = __uint_as_float(__float_as_uint(M0) ^ sgn0);
        const float e1 = __uint_as_float(__float_as_uint(M1) ^ sgn1);
        const float h0 = y1lo - e0;
        const float h1 = y1hi - e1;
        unsigned pk = (unsigned)__bfloat16_as_ushort(__float2bfloat16(h0))
                    | ((unsigned)__bfloat16_as_ushort(__float2bfloat16(h1)) << 16);
        hselp[(size_t)(ra + half) * 32 + c2] = pk;
        // sum_k (y1-v) = 16 y1 - s2 ; sum_k (y1-v)^2 = (16 y1 - 2 s2) y1 + q2
        ssum0 += 16.f * y1lo - s20;
        ssum1 += 16.f * y1hi - s21;
        ssq0  += fmaf(fmaf(-2.f, s20, 16.f * y1lo), y1lo, q20);
        ssq1  += fmaf(fmaf(-2.f, s21, 16.f * y1hi), y1hi, q21);
    }

    __shared__ float rs[8][64];
    __shared__ float rq[8][64];
    rs[w * 2 + half][c2 * 2]     = ssum0;
    rs[w * 2 + half][c2 * 2 + 1] = ssum1;
    rq[w * 2 + half][c2 * 2]     = ssq0;
    rq[w * 2 + half][c2 * 2 + 1] = ssq1;
    __syncthreads();
    if (tid < 128) {
        const int c = tid & 63;
        float v = 0.f;
        if (tid < 64) {
            #pragma unroll
            for (int r = 0; r < 8; ++r) v += rs[r][c];
        } else {
            #pragma unroll
            for (int r = 0; r < 8; ++r) v += rq[r][c];
        }
        partials[(size_t)g * 128 + tid] = v;   // plain coalesced store
    }
}

// ---------------- Kernel 3: parallel reduce partials -> stats ----------------
__global__ __launch_bounds__(256) void reduce_kernel(
    const float* __restrict__ partials,      // (2048, 128)
    float* __restrict__ stats)               // [0..63]=sum, [64..127]=sumsq
{
    __shared__ float lds[256];
    const int tid = threadIdx.x;
    const int c   = tid & 127;
    const int q   = tid >> 7;
    const int r0  = blockIdx.x * 32 + q * 16;
    float acc = 0.f;
    #pragma unroll
    for (int r = 0; r < 16; ++r)
        acc += partials[(size_t)(r0 + r) * 128 + c];
    lds[tid] = acc;
    __syncthreads();
    if (tid < 128) atomicAdd(&stats[tid], lds[tid] + lds[tid + 128]);
}

// ---------------- Kernel 4: finalize + affine + leaky + transpose ----------------
__global__ __launch_bounds__(256) void out_kernel(
    const unsigned* __restrict__ hselp,      // (B,N,32) bf16-pairs
    const float* __restrict__ stats,
    const float* __restrict__ gamma,
    const float* __restrict__ beta,
    float* __restrict__ out)                 // (B, 64, N)
{
    __shared__ float tile[64 * 65];
    __shared__ float sc[64], bi[64];
    const int tid = threadIdx.x;
    if (tid < 64) {
        float mean = stats[tid] * (1.0f / BNK_F);
        float var  = stats[64 + tid] * (1.0f / BNK_F) - mean * mean;
        float s    = gamma[tid] * rsqrtf(var + 1e-5f);
        sc[tid] = s;
        bi[tid] = beta[tid] - mean * s;
    }
    __syncthreads();

    const int b  = blockIdx.x >> 8;
    const int n0 = (blockIdx.x & 255) << 6;
    const size_t bn0 = (size_t)b * NDIM + n0;
    const int c2 = tid & 31;
    const int r0 = tid >> 5;                 // 8 rows per pass

    for (int r = r0; r < 64; r += 8) {
        unsigned u = hselp[(bn0 + r) * 32 + c2];
        float v0 = fmaf(sc[2 * c2],     __uint_as_float(u << 16),          bi[2 * c2]);
        float v1 = fmaf(sc[2 * c2 + 1], __uint_as_float(u & 0xffff0000u), bi[2 * c2 + 1]);
        v0 = (v0 >= 0.f) ? v0 : 0.2f * v0;
        v1 = (v1 >= 0.f) ? v1 : 0.2f * v1;
        tile[r * 65 + 2 * c2]     = v0;
        tile[r * 65 + 2 * c2 + 1] = v1;
    }
    __syncthreads();
    const int lane = tid & 63;
    for (int o = tid >> 6; o < 64; o += 4)
        out[((size_t)(b * 64 + o) << 14) + n0 + lane] = tile[lane * 65 + o];
}

extern "C" void kernel_launch(void* const* d_in, const int* in_sizes, int n_in,
                              void* d_out, int out_size, void* d_ws, size_t ws_size,
                              hipStream_t stream) {
    const float* x     = (const float*)d_in[0];
    const int*   ei    = (const int*)d_in[1];
    const float* W     = (const float*)d_in[2];
    const float* gamma = (const float*)d_in[3];
    const float* beta  = (const float*)d_in[4];
    float* out = (float*)d_out;

    char* ws = (char*)d_ws;
    __hip_bfloat16* y1    = (__hip_bfloat16*)(ws);                // 8 MiB
    __hip_bfloat16* y2    = (__hip_bfloat16*)(ws + 8388608);      // 8 MiB
    unsigned*       hselp = (unsigned*)(ws + 16777216);           // 8 MiB (bf16 pairs)
    float*          part  = (float*)(ws + 25165824);              // 1 MiB
    float*          stats = (float*)(ws + 25165824 + 1048576);    // 512 B

    gemm_y_kernel <<<dim3(1024), dim3(256), 0, stream>>>(x, W, y1, y2, stats);
    gather_kernel <<<dim3(2048), dim3(256), 0, stream>>>((const unsigned*)y1, (const unsigned*)y2,
                                                         ei, gamma, hselp, part);
    reduce_kernel <<<dim3(64),   dim3(256), 0, stream>>>(part, stats);
    out_kernel    <<<dim3(1024), dim3(256), 0, stream>>>(hselp, stats, gamma, beta, out);
}